// Round 4
// baseline (134.987 us; speedup 1.0000x reference)
//
#include <hip/hip_runtime.h>

// Chunked fast-weight linear attention, MI355X gfx950 — 3-kernel decomposition.
// K1 ttr_pt:     P_c = k_c^T v_c per (bh,chunk)            [1024 wgs]
// K2 ttr_prefix: W_c = exclusive prefix of P               [256 wgs]
// K3 ttr_out:    out = (mask(q k^T) v + q W_prev) / t      [4096 wgs]
// R4: ttr_out reworked — q in registers (wave-private rows), LDS 40KB ->
// 3 wgs/CU, v-quarter split with sibling-adjacent XCD-aware remap so the
// 4 wgs sharing (bh,c) are concurrent on one XCD (L2-hot q,k), 2 barriers.

typedef _Float16 f16;
typedef __attribute__((ext_vector_type(4))) _Float16 f16x4;
typedef __attribute__((ext_vector_type(8))) _Float16 f16x8;
typedef __attribute__((ext_vector_type(4))) float f32x4;
typedef __attribute__((ext_vector_type(16))) float f32x16;
typedef __attribute__((ext_vector_type(4))) float fv4;

#define MFMA16(a, b, c) __builtin_amdgcn_mfma_f32_16x16x32_f16((a), (b), (c), 0, 0, 0)
#define MFMA32(a, b, c) __builtin_amdgcn_mfma_f32_32x32x16_f16((a), (b), (c), 0, 0, 0)

// Byte offset into a row-major [*][128] f16 LDS tile; XOR key mixes row bits
// 0-2 and 3-5 so both 16-row and 32-row fragment reads spread evenly over
// banks. Consistent across all writers/readers -> layout-correct.
__device__ __forceinline__ int swzb(int row, int col) {
  int s = (row ^ (row >> 3)) & 7;
  return (row << 8) + ((col << 1) ^ (s << 4));
}

// 32x32x16 operand fragment: row = lane&31, k = kk*16 + 8*(lane>>5) + j.
// Same k-map on A and B operands -> contraction correct. One ds_read_b128.
__device__ __forceinline__ f16x8 frag32(const f16* lds, int row, int kk, int lane) {
  int c0 = (kk << 4) + ((lane >> 5) << 3);
  return *(const f16x8*)((const char*)lds + swzb(row, c0));
}

// 32x32 C/D row for acc reg r, lane-half g: row=(r&3)+8*(r>>2)+4*g  [m74/m101]
__device__ __forceinline__ int rowf(int r, int g) {
  return (r & 3) + ((r >> 2) << 3) + (g << 2);
}

// ---------------------------------------------------------------------------
// K1: P_c^T[v][f] = sum_s v[s][v] * k[s][f]
__global__ __launch_bounds__(512, 1)
void ttr_pt(const float* __restrict__ k, const float* __restrict__ v,
            f16* __restrict__ pt) {
  __shared__ f16 kT[128 * 128];
  __shared__ f16 vT[128 * 128];
  const int tid = threadIdx.x, lane = tid & 63, wave = tid >> 6;
  const int bh = blockIdx.x >> 5, c = blockIdx.x & 31;
  const float* kg = k + ((size_t)bh * 4096 + c * 128) * 128;
  const float* vg = v + ((size_t)bh * 4096 + c * 128) * 128;
  const int f0 = (tid & 31) << 2;
#pragma unroll
  for (int p = 0; p < 8; ++p) {
    int s = (p << 4) + (tid >> 5);
    fv4 xk = *(const fv4*)(kg + s * 128 + f0);
    fv4 xv = *(const fv4*)(vg + s * 128 + f0);
#pragma unroll
    for (int e = 0; e < 4; ++e) {
      *(f16*)((char*)kT + swzb(f0 + e, s)) = (f16)xk[e];
      *(f16*)((char*)vT + swzb(f0 + e, s)) = (f16)xv[e];
    }
  }
  __syncthreads();
  const int l31 = lane & 31, g = lane >> 5;
  const int mt = wave >> 1, nt0 = (wave & 1) << 1;
  f32x16 p0 = {0.f}, p1 = {0.f};
#pragma unroll
  for (int kk = 0; kk < 8; ++kk) {
    f16x8 a = frag32(vT, (mt << 5) + l31, kk, lane);
    p0 = MFMA32(a, frag32(kT, (nt0 << 5) + l31, kk, lane), p0);
    p1 = MFMA32(a, frag32(kT, ((nt0 + 1) << 5) + l31, kk, lane), p1);
  }
  f16* dst = pt + (size_t)blockIdx.x * 16384;
#pragma unroll
  for (int r = 0; r < 16; ++r) {
    int vr = (mt << 5) + rowf(r, g);
    dst[vr * 128 + (nt0 << 5) + l31] = (f16)p0[r];
    dst[vr * 128 + ((nt0 + 1) << 5) + l31] = (f16)p1[r];
  }
}

// ---------------------------------------------------------------------------
// K2: exclusive prefix over chunks; output in B-frag-permuted layout:
// 16B unit (NT,kk,g,laneC) holds W[v=NT*32+g*0..][f=kk*16+8g..+7] per lane.
__global__ __launch_bounds__(256, 1)
void ttr_prefix(const f16* __restrict__ pt, f16* __restrict__ w) {
  __shared__ f16 xch[256 * 8];
  const int tid = threadIdx.x;
  const int bh = blockIdx.x >> 3, vs = blockIdx.x & 7;
  const int v0 = vs << 4;
  const int NT = v0 >> 5;
  const int vloc = tid >> 4, fblk = tid & 15;
  const size_t bhbase = (size_t)bh * 32 * 16384;
  const f16* src = pt + bhbase + (size_t)(v0 + vloc) * 128 + fblk * 8;
  const int kk = tid >> 5, gg = (tid >> 4) & 1, lc = tid & 15;
  f16* dstu = w + bhbase +
              (size_t)(((NT * 8 + kk) * 64) + gg * 32 + (v0 & 31) + lc) * 8;
  const int phi_w = vloc * 16 + (fblk ^ vloc);
  const int phi_r = lc * 16 + ((tid >> 4) ^ lc);
  float acc[8];
#pragma unroll
  for (int e = 0; e < 8; ++e) acc[e] = 0.f;
  for (int c = 0; c < 32; ++c) {
    f16x8 pcur = *(const f16x8*)(src + (size_t)c * 16384);
    f16x8 h;
#pragma unroll
    for (int e = 0; e < 8; ++e) h[e] = (f16)acc[e];
    *(f16x8*)(xch + phi_w * 8) = h;
    __syncthreads();
    f16x8 o = *(const f16x8*)(xch + phi_r * 8);
    *(f16x8*)(dstu + (size_t)c * 16384) = o;
    __syncthreads();
#pragma unroll
    for (int e = 0; e < 8; ++e) acc[e] += (float)pcur[e];
  }
}

// ---------------------------------------------------------------------------
// K3: wg = (bh, c, v-quarter). 4 waves; wave m owns out rows [32m,32m+32).
// q in registers (wave-private rows); LDS = k/S (32KB) + vT (8KB) = 40KB.
__global__ __launch_bounds__(256, 3)
void ttr_out(const float* __restrict__ q, const float* __restrict__ k,
             const float* __restrict__ v, const f16* __restrict__ w,
             float* __restrict__ out) {
  __shared__ f16 s_lds[128 * 128];  // 32KB: k, then masked S (in place)
  __shared__ f16 vT[32 * 128];      // 8KB: v-quarter transposed
  const int tid = threadIdx.x, lane = tid & 63, wave = tid >> 6;
  const int l31 = lane & 31, g = lane >> 5;
  // sibling remap: 4 siblings of group gidx are adjacent (same 32-window)
  // and differ by 8 (same XCD under round-robin) -> concurrent L2 reuse.
  const int widx = blockIdx.x & 31;
  const int gidx = ((blockIdx.x >> 5) << 3) + (widx & 7);  // (bh,c) in [0,1024)
  const int vq = widx >> 3;                                // v-quarter 0..3
  const int bh = gidx >> 5, c = gidx & 31;
  const float* qg = q + ((size_t)bh * 4096 + c * 128) * 128;
  const float* kg = k + ((size_t)bh * 4096 + c * 128) * 128;
  const float* vg = v + ((size_t)bh * 4096 + c * 128) * 128 + vq * 32;

  // W B-frags straight from global (K2's permuted layout), issued first
  const f16* wb = w + (size_t)gidx * 16384;
  f16x8 wf[8];
#pragma unroll
  for (int kk = 0; kk < 8; ++kk)
    wf[kk] = *(const f16x8*)(wb + (size_t)(((vq * 8 + kk) * 64) + lane) * 8);

  // q A-frags: wave-private rows, col = kk*16 + 8g + j (frag32 k-map)
  f16x8 qf[8];
  {
    const float* qr = qg + ((wave << 5) + l31) * 128 + (g << 3);
#pragma unroll
    for (int kk = 0; kk < 8; ++kk) {
      fv4 a = *(const fv4*)(qr + (kk << 4));
      fv4 b = *(const fv4*)(qr + (kk << 4) + 4);
      f16x8 h = {(f16)a[0], (f16)a[1], (f16)a[2], (f16)a[3],
                 (f16)b[0], (f16)b[1], (f16)b[2], (f16)b[3]};
      qf[kk] = h;
    }
  }

  // stage k (f32 -> f16, swizzled)
  {
    const int c0 = (tid & 31) << 2;
#pragma unroll
    for (int p = 0; p < 16; ++p) {
      int s = (p << 3) + (tid >> 5);
      fv4 xk = *(const fv4*)(kg + s * 128 + c0);
      f16x4 hk = {(f16)xk[0], (f16)xk[1], (f16)xk[2], (f16)xk[3]};
      *(f16x4*)((char*)s_lds + swzb(s, c0)) = hk;
    }
  }
  // stage vT (v-quarter transposed; vT row = local v-col 0..31, col = s)
  {
    const int c0 = (tid & 7) << 2;
#pragma unroll
    for (int p = 0; p < 4; ++p) {
      int s = (p << 5) + (tid >> 3);
      fv4 xv = *(const fv4*)(vg + s * 128 + c0);
#pragma unroll
      for (int e = 0; e < 4; ++e)
        *(f16*)((char*)vT + swzb(c0 + e, s)) = (f16)xv[e];
    }
  }
  __syncthreads();  // B1: k, vT staged

  // S tiles (wave, j<=wave) + qW fused (shared A-frag). Static accum indices.
  f32x16 s0 = {0.f}, s1 = {0.f}, s2 = {0.f}, s3 = {0.f}, o0 = {0.f};
#pragma unroll
  for (int kk = 0; kk < 8; ++kk) {
    f16x8 aq = qf[kk];
    o0 = MFMA32(aq, wf[kk], o0);
    s0 = MFMA32(aq, frag32(s_lds, l31, kk, lane), s0);
    if (wave >= 1) s1 = MFMA32(aq, frag32(s_lds, 32 + l31, kk, lane), s1);
    if (wave >= 2) s2 = MFMA32(aq, frag32(s_lds, 64 + l31, kk, lane), s2);
    if (wave >= 3) s3 = MFMA32(aq, frag32(s_lds, 96 + l31, kk, lane), s3);
  }
  __syncthreads();  // B2: all k reads done; s_lds rows become wave-private S

  // masked S -> s_lds rows [32*wave, 32*wave+32) (own rows only)
#define STORE_S(ACC, J)                                                       \
  {                                                                           \
    const bool dg = ((J) == wave);                                            \
    _Pragma("unroll") for (int r = 0; r < 16; ++r) {                          \
      int rl = rowf(r, g);                                                    \
      float val = ACC[r];                                                     \
      if (dg && l31 > rl) val = 0.f;                                          \
      *(f16*)((char*)s_lds + swzb((wave << 5) + rl, ((J) << 5) + l31)) =      \
          (f16)val;                                                           \
    }                                                                         \
  }
  STORE_S(s0, 0);
  if (wave >= 1) STORE_S(s1, 1);
  if (wave >= 2) STORE_S(s2, 2);
  if (wave >= 3) STORE_S(s3, 3);
  // no barrier: each wave reads only its own S rows (ds lgkmcnt suffices)

  // Sv over the causal k-range
  const int nkk = (wave + 1) << 1;
  for (int kk = 0; kk < nkk; ++kk)
    o0 = MFMA32(frag32(s_lds, (wave << 5) + l31, kk, lane),
                frag32(vT, l31, kk, lane), o0);

  float* og = out + (((size_t)bh * 4096) + c * 128 + (wave << 5)) * 128 + vq * 32;
#pragma unroll
  for (int r = 0; r < 16; ++r) {
    int rl = rowf(r, g);
    float tg = (float)(c * 128 + (wave << 5) + rl + 1);
    og[rl * 128 + l31] = o0[r] / tg;
  }
}

extern "C" void kernel_launch(void* const* d_in, const int* in_sizes, int n_in,
                              void* d_out, int out_size, void* d_ws, size_t ws_size,
                              hipStream_t stream) {
  const float* q = (const float*)d_in[0];
  const float* k = (const float*)d_in[1];
  const float* v = (const float*)d_in[2];
  float* o = (float*)d_out;
  f16* pt = (f16*)d_ws;
  f16* w = pt + (size_t)32 * 32 * 16384;
  ttr_pt<<<dim3(1024), dim3(512), 0, stream>>>(k, v, pt);
  ttr_prefix<<<dim3(256), dim3(256), 0, stream>>>(pt, w);
  ttr_out<<<dim3(4096), dim3(256), 0, stream>>>(q, k, v, w, o);
}

// Round 5
// 107.092 us; speedup vs baseline: 1.2605x; 1.2605x over previous
//
#include <hip/hip_runtime.h>

// Chunked fast-weight linear attention, MI355X gfx950 — 3-kernel decomposition.
// K1 ttr_pt:     P_c = k_c^T v_c per (bh,chunk)            [1024 wgs]
// K2 ttr_prefix: W_c = exclusive prefix of P               [256 wgs]
// K3 ttr_out:    out = (mask(q k^T) v + q W_prev) / t      [4096 wgs]
// R5: K3 fixed — R4 spilled ~48B/thread (WRITE_SIZE 64->112 MiB). W quarter
// now staged in LDS (frees 32 VGPRs; K2 layout = contiguous 8KB per wg),
// qW after STORE_S, v_rcp epilogue. LDS 48KB -> 3 wg/CU. Sibling remap kept.

typedef _Float16 f16;
typedef __attribute__((ext_vector_type(4))) _Float16 f16x4;
typedef __attribute__((ext_vector_type(8))) _Float16 f16x8;
typedef __attribute__((ext_vector_type(4))) float f32x4;
typedef __attribute__((ext_vector_type(16))) float f32x16;
typedef __attribute__((ext_vector_type(4))) float fv4;

#define MFMA32(a, b, c) __builtin_amdgcn_mfma_f32_32x32x16_f16((a), (b), (c), 0, 0, 0)

// Byte offset into a row-major [*][128] f16 LDS tile; XOR key mixes row bits
// 0-2 and 3-5 so both 16-row and 32-row fragment reads spread evenly over
// banks. Consistent across all writers/readers -> layout-correct.
__device__ __forceinline__ int swzb(int row, int col) {
  int s = (row ^ (row >> 3)) & 7;
  return (row << 8) + ((col << 1) ^ (s << 4));
}

// 32x32x16 operand fragment: row = lane&31, k = kk*16 + 8*(lane>>5) + j.
// Same k-map on A and B operands -> contraction correct. One ds_read_b128.
__device__ __forceinline__ f16x8 frag32(const f16* lds, int row, int kk, int lane) {
  int c0 = (kk << 4) + ((lane >> 5) << 3);
  return *(const f16x8*)((const char*)lds + swzb(row, c0));
}

// 32x32 C/D row for acc reg r, lane-half g: row=(r&3)+8*(r>>2)+4*g  [m74/m101]
__device__ __forceinline__ int rowf(int r, int g) {
  return (r & 3) + ((r >> 2) << 3) + (g << 2);
}

// ---------------------------------------------------------------------------
// K1: P_c^T[v][f] = sum_s v[s][v] * k[s][f]
__global__ __launch_bounds__(512, 1)
void ttr_pt(const float* __restrict__ k, const float* __restrict__ v,
            f16* __restrict__ pt) {
  __shared__ f16 kT[128 * 128];
  __shared__ f16 vT[128 * 128];
  const int tid = threadIdx.x, lane = tid & 63, wave = tid >> 6;
  const int bh = blockIdx.x >> 5, c = blockIdx.x & 31;
  const float* kg = k + ((size_t)bh * 4096 + c * 128) * 128;
  const float* vg = v + ((size_t)bh * 4096 + c * 128) * 128;
  const int f0 = (tid & 31) << 2;
#pragma unroll
  for (int p = 0; p < 8; ++p) {
    int s = (p << 4) + (tid >> 5);
    fv4 xk = *(const fv4*)(kg + s * 128 + f0);
    fv4 xv = *(const fv4*)(vg + s * 128 + f0);
#pragma unroll
    for (int e = 0; e < 4; ++e) {
      *(f16*)((char*)kT + swzb(f0 + e, s)) = (f16)xk[e];
      *(f16*)((char*)vT + swzb(f0 + e, s)) = (f16)xv[e];
    }
  }
  __syncthreads();
  const int l31 = lane & 31, g = lane >> 5;
  const int mt = wave >> 1, nt0 = (wave & 1) << 1;
  f32x16 p0 = {0.f}, p1 = {0.f};
#pragma unroll
  for (int kk = 0; kk < 8; ++kk) {
    f16x8 a = frag32(vT, (mt << 5) + l31, kk, lane);
    p0 = MFMA32(a, frag32(kT, (nt0 << 5) + l31, kk, lane), p0);
    p1 = MFMA32(a, frag32(kT, ((nt0 + 1) << 5) + l31, kk, lane), p1);
  }
  f16* dst = pt + (size_t)blockIdx.x * 16384;
#pragma unroll
  for (int r = 0; r < 16; ++r) {
    int vr = (mt << 5) + rowf(r, g);
    dst[vr * 128 + (nt0 << 5) + l31] = (f16)p0[r];
    dst[vr * 128 + ((nt0 + 1) << 5) + l31] = (f16)p1[r];
  }
}

// ---------------------------------------------------------------------------
// K2: exclusive prefix over chunks; output in B-frag-permuted layout:
// per (bh,c), 16B unit u = (NT*8+kk)*64 + g*32 + laneC holds
// W[v = NT*32 + laneC][f = kk*16 + 8g .. +7]. Quarter NT is 8KB contiguous.
__global__ __launch_bounds__(256, 1)
void ttr_prefix(const f16* __restrict__ pt, f16* __restrict__ w) {
  __shared__ f16 xch[256 * 8];
  const int tid = threadIdx.x;
  const int bh = blockIdx.x >> 3, vs = blockIdx.x & 7;
  const int v0 = vs << 4;
  const int NT = v0 >> 5;
  const int vloc = tid >> 4, fblk = tid & 15;
  const size_t bhbase = (size_t)bh * 32 * 16384;
  const f16* src = pt + bhbase + (size_t)(v0 + vloc) * 128 + fblk * 8;
  const int kk = tid >> 5, gg = (tid >> 4) & 1, lc = tid & 15;
  f16* dstu = w + bhbase +
              (size_t)(((NT * 8 + kk) * 64) + gg * 32 + (v0 & 31) + lc) * 8;
  const int phi_w = vloc * 16 + (fblk ^ vloc);
  const int phi_r = lc * 16 + ((tid >> 4) ^ lc);
  float acc[8];
#pragma unroll
  for (int e = 0; e < 8; ++e) acc[e] = 0.f;
  for (int c = 0; c < 32; ++c) {
    f16x8 pcur = *(const f16x8*)(src + (size_t)c * 16384);
    f16x8 h;
#pragma unroll
    for (int e = 0; e < 8; ++e) h[e] = (f16)acc[e];
    *(f16x8*)(xch + phi_w * 8) = h;
    __syncthreads();
    f16x8 o = *(const f16x8*)(xch + phi_r * 8);
    *(f16x8*)(dstu + (size_t)c * 16384) = o;
    __syncthreads();
#pragma unroll
    for (int e = 0; e < 8; ++e) acc[e] += (float)pcur[e];
  }
}

// ---------------------------------------------------------------------------
// K3: wg = (bh, c, v-quarter). 4 waves; wave m owns out rows [32m,32m+32).
// q in regs; k/S + vT + W in LDS (48KB -> 3 wg/CU). 2 barriers.
__global__ __launch_bounds__(256, 3)
void ttr_out(const float* __restrict__ q, const float* __restrict__ k,
             const float* __restrict__ v, const f16* __restrict__ w,
             float* __restrict__ out) {
  __shared__ f16 s_lds[128 * 128];  // 32KB: k, then masked S (in place)
  __shared__ f16 vT[32 * 128];      // 8KB: v-quarter transposed
  __shared__ f16 w_lds[512 * 8];    // 8KB: W quarter, frag-unit order
  const int tid = threadIdx.x, lane = tid & 63, wave = tid >> 6;
  const int l31 = lane & 31, g = lane >> 5;
  // sibling remap: the 4 wgs sharing (bh,c) are adjacent in dispatch and
  // congruent mod 8 -> same XCD, concurrent -> q/k L2-hot.
  const int widx = blockIdx.x & 31;
  const int gidx = ((blockIdx.x >> 5) << 3) + (widx & 7);  // (bh,c) in [0,1024)
  const int vq = widx >> 3;                                // v-quarter 0..3
  const int bh = gidx >> 5, c = gidx & 31;
  const float* qg = q + ((size_t)bh * 4096 + c * 128) * 128;
  const float* kg = k + ((size_t)bh * 4096 + c * 128) * 128;
  const float* vg = v + ((size_t)bh * 4096 + c * 128) * 128 + vq * 32;

  // W quarter: contiguous 8KB in K2's layout — issue the loads FIRST
  const f16* wsrc = w + (size_t)gidx * 16384 + vq * 4096;
  f16x8 wl0 = *(const f16x8*)(wsrc + tid * 8);
  f16x8 wl1 = *(const f16x8*)(wsrc + (256 + tid) * 8);

  // q A-frags: wave-private rows, col = kk*16 + 8g + j (frag32 k-map)
  f16x8 qf[8];
  {
    const float* qr = qg + ((wave << 5) + l31) * 128 + (g << 3);
#pragma unroll
    for (int kk = 0; kk < 8; ++kk) {
      fv4 a = *(const fv4*)(qr + (kk << 4));
      fv4 b = *(const fv4*)(qr + (kk << 4) + 4);
      f16x8 h = {(f16)a[0], (f16)a[1], (f16)a[2], (f16)a[3],
                 (f16)b[0], (f16)b[1], (f16)b[2], (f16)b[3]};
      qf[kk] = h;
    }
  }
  // stage k (f32 -> f16, swizzled)
  {
    const int c0 = (tid & 31) << 2;
#pragma unroll
    for (int p = 0; p < 16; ++p) {
      int s = (p << 3) + (tid >> 5);
      fv4 xk = *(const fv4*)(kg + s * 128 + c0);
      f16x4 hk = {(f16)xk[0], (f16)xk[1], (f16)xk[2], (f16)xk[3]};
      *(f16x4*)((char*)s_lds + swzb(s, c0)) = hk;
    }
  }
  // stage vT (v-quarter transposed; vT row = local v-col 0..31, col = s)
  {
    const int c0 = (tid & 7) << 2;
#pragma unroll
    for (int p = 0; p < 4; ++p) {
      int s = (p << 5) + (tid >> 3);
      fv4 xv = *(const fv4*)(vg + s * 128 + c0);
#pragma unroll
      for (int e = 0; e < 4; ++e)
        *(f16*)((char*)vT + swzb(c0 + e, s)) = (f16)xv[e];
    }
  }
  // W regs -> LDS (unit u at w_lds + u*8; reads are lane-contiguous)
  *(f16x8*)(w_lds + tid * 8) = wl0;
  *(f16x8*)(w_lds + (256 + tid) * 8) = wl1;
  __syncthreads();  // B1: k, vT, W staged

  // S tiles (wave, j<=wave). Static accum indices; wave-uniform guards.
  f32x16 s0 = {0.f}, s1 = {0.f}, s2 = {0.f}, s3 = {0.f}, o0 = {0.f};
#pragma unroll
  for (int kk = 0; kk < 8; ++kk) {
    f16x8 aq = qf[kk];
    s0 = MFMA32(aq, frag32(s_lds, l31, kk, lane), s0);
    if (wave >= 1) s1 = MFMA32(aq, frag32(s_lds, 32 + l31, kk, lane), s1);
    if (wave >= 2) s2 = MFMA32(aq, frag32(s_lds, 64 + l31, kk, lane), s2);
    if (wave >= 3) s3 = MFMA32(aq, frag32(s_lds, 96 + l31, kk, lane), s3);
  }
  __syncthreads();  // B2: all k reads done; s_lds rows become wave-private S

  // masked S -> s_lds rows [32*wave, 32*wave+32) (own rows only; no barrier
  // needed after — each wave re-reads only its own rows, lgkmcnt orders it)
#define STORE_S(ACC, J)                                                       \
  {                                                                           \
    const bool dg = ((J) == wave);                                            \
    _Pragma("unroll") for (int r = 0; r < 16; ++r) {                          \
      int rl = rowf(r, g);                                                    \
      float val = ACC[r];                                                     \
      if (dg && l31 > rl) val = 0.f;                                          \
      *(f16*)((char*)s_lds + swzb((wave << 5) + rl, ((J) << 5) + l31)) =      \
          (f16)val;                                                           \
    }                                                                         \
  }
  STORE_S(s0, 0);
  if (wave >= 1) STORE_S(s1, 1);
  if (wave >= 2) STORE_S(s2, 2);
  if (wave >= 3) STORE_S(s3, 3);

  // qW while the S stores drain (w_lds reads: unit kk*64+lane, conflict-free)
#pragma unroll
  for (int kk = 0; kk < 8; ++kk)
    o0 = MFMA32(qf[kk], *(const f16x8*)(w_lds + ((kk << 6) + lane) * 8), o0);

  // Sv over the causal k-range
  const int nkk = (wave + 1) << 1;
  for (int kk = 0; kk < nkk; ++kk)
    o0 = MFMA32(frag32(s_lds, (wave << 5) + l31, kk, lane),
                frag32(vT, l31, kk, lane), o0);

  float* og = out + (((size_t)bh * 4096) + c * 128 + (wave << 5)) * 128 + vq * 32;
#pragma unroll
  for (int r = 0; r < 16; ++r) {
    int rl = rowf(r, g);
    float tg = (float)(c * 128 + (wave << 5) + rl + 1);
    og[rl * 128 + l31] = o0[r] * __builtin_amdgcn_rcpf(tg);  // |rel|~1e-5 ok
  }
}

extern "C" void kernel_launch(void* const* d_in, const int* in_sizes, int n_in,
                              void* d_out, int out_size, void* d_ws, size_t ws_size,
                              hipStream_t stream) {
  const float* q = (const float*)d_in[0];
  const float* k = (const float*)d_in[1];
  const float* v = (const float*)d_in[2];
  float* o = (float*)d_out;
  f16* pt = (f16*)d_ws;
  f16* w = pt + (size_t)32 * 32 * 16384;
  ttr_pt<<<dim3(1024), dim3(512), 0, stream>>>(k, v, pt);
  ttr_prefix<<<dim3(256), dim3(256), 0, stream>>>(pt, w);
  ttr_out<<<dim3(4096), dim3(256), 0, stream>>>(q, k, v, w, o);
}